// Round 2
// baseline (91.980 us; speedup 1.0000x reference)
//
#include <hip/hip_runtime.h>

#define BATCH 4
#define T 4096
#define D 128
#define CHUNKS 128             // stage-1 blocks per batch
#define ROWS1 32               // rows per stage-1 block (T / CHUNKS)
#define ROWS2 64               // rows per stage-2 block
#define XS_STRIDE 132          // padded LDS stride for stage 2 (528B: keeps b128 aligned)

// ---------------- Stage 1: partial Gram matrices -----------------
// grid = BATCH*CHUNKS = 512 blocks of 256 threads -> 2 blocks/CU, 2 waves/SIMD.
// Each block: G_part[d1][d2] = sum over its 32 rows of X[t,d1]*X[t,d2].
// Thread tile 8x8 (rows ty*8, cols {tx*4, 64+tx*4}) — LDS:FMA optimal ratio,
// all LDS reads broadcast or contiguous-b128 (conflict-free).
__global__ __launch_bounds__(256) void k_partial_g(const float* __restrict__ x,
                                                   float* __restrict__ part) {
    __shared__ float Xs[ROWS1 * D];          // 16 KB
    const int blk = blockIdx.x;
    const int b = blk >> 7, chunk = blk & (CHUNKS - 1);
    const float* xp = x + ((size_t)b * T + (size_t)chunk * ROWS1) * D;
    const int tid = threadIdx.x;

    const float4* xp4 = (const float4*)xp;
    float4* Xs4 = (float4*)Xs;
    #pragma unroll
    for (int i = 0; i < (ROWS1 * D / 4) / 256; i++)
        Xs4[tid + i * 256] = xp4[tid + i * 256];
    __syncthreads();

    const int ty = tid >> 4, tx = tid & 15;
    const int r0 = ty * 8;
    const int c0 = tx * 4;

    float acc[8][8];
    #pragma unroll
    for (int i = 0; i < 8; i++)
        #pragma unroll
        for (int j = 0; j < 8; j++) acc[i][j] = 0.f;

    #pragma unroll 4
    for (int t = 0; t < ROWS1; t++) {
        const float* row = Xs + t * D;
        float a[8], bv[8];
        #pragma unroll
        for (int i = 0; i < 8; i++) a[i] = row[r0 + i];
        #pragma unroll
        for (int j = 0; j < 4; j++) { bv[j] = row[c0 + j]; bv[4 + j] = row[64 + c0 + j]; }
        #pragma unroll
        for (int i = 0; i < 8; i++)
            #pragma unroll
            for (int j = 0; j < 8; j++) acc[i][j] += a[i] * bv[j];
    }

    float* pp = part + (size_t)blk * (D * D);
    #pragma unroll
    for (int i = 0; i < 8; i++) {
        *(float4*)(pp + (r0 + i) * D + c0)      = make_float4(acc[i][0], acc[i][1], acc[i][2], acc[i][3]);
        *(float4*)(pp + (r0 + i) * D + 64 + c0) = make_float4(acc[i][4], acc[i][5], acc[i][6], acc[i][7]);
    }
}

// ---------------- Stage 1b: reduce partials -> G -----------------
// grid = BATCH*D*D/256 = 256 blocks. Each thread sums CHUNKS strided values
// with 8 independent accumulators (deep memory-level parallelism).
__global__ __launch_bounds__(256) void k_reduce_g(const float* __restrict__ part,
                                                  float* __restrict__ g) {
    const int o = blockIdx.x * 256 + threadIdx.x;   // 0 .. BATCH*D*D
    const int b = o >> 14;                          // / 16384
    const int e = o & 16383;
    const float* p = part + ((size_t)b * CHUNKS) * (D * D) + e;
    float s[8];
    #pragma unroll
    for (int i = 0; i < 8; i++) s[i] = 0.f;
    #pragma unroll 4
    for (int c = 0; c < CHUNKS; c += 8) {
        #pragma unroll
        for (int i = 0; i < 8; i++)
            s[i] += p[(size_t)(c + i) * (D * D)];
    }
    g[o] = ((s[0] + s[1]) + (s[2] + s[3])) + ((s[4] + s[5]) + (s[6] + s[7]));
}

// ---------------- Stage 2: out = X * G ---------------------------
// grid = BATCH*64 = 256 blocks of 512 threads (8 waves -> 2/SIMD).
// 64-row x 128-col tile; thread micro-tile 4x4. k processed in groups of 4
// so every LDS read is ds_read_b128: X rows (aligned via stride 132) and
// G rows (contiguous across lanes).
__global__ __launch_bounds__(512) void k_xg(const float* __restrict__ x,
                                            const float* __restrict__ g,
                                            float* __restrict__ out) {
    __shared__ float Xs[ROWS2 * XS_STRIDE];  // 33 KB
    __shared__ float Gs[32 * D];             // 16 KB
    const int blk = blockIdx.x;
    const int b = blk >> 6, chunk = blk & 63;
    const float* xp = x + ((size_t)b * T + (size_t)chunk * ROWS2) * D;
    const int tid = threadIdx.x;

    #pragma unroll
    for (int ii = 0; ii < (ROWS2 * D / 4) / 512; ii++) {
        int i = tid + ii * 512;
        int t = i >> 5, c4 = i & 31;
        *(float4*)(Xs + t * XS_STRIDE + c4 * 4) = ((const float4*)xp)[i];
    }

    const int ty = tid >> 5;                 // 0..15  -> row group
    const int cx = tid & 31;                 // 0..31  -> col group
    const int r0 = ty * 4;
    const int c0 = cx * 4;

    float acc[4][4];
    #pragma unroll
    for (int i = 0; i < 4; i++)
        #pragma unroll
        for (int j = 0; j < 4; j++) acc[i][j] = 0.f;

    const float* gb = g + (size_t)b * (D * D);
    for (int kt = 0; kt < D; kt += 32) {
        __syncthreads();                     // also covers initial Xs fill
        #pragma unroll
        for (int ii = 0; ii < (32 * D / 4) / 512; ii++)
            ((float4*)Gs)[tid + ii * 512] = ((const float4*)(gb + kt * D))[tid + ii * 512];
        __syncthreads();
        #pragma unroll
        for (int kk = 0; kk < 32; kk += 4) {
            float4 xa[4], gv[4];
            #pragma unroll
            for (int i = 0; i < 4; i++)
                xa[i] = *(const float4*)(Xs + (r0 + i) * XS_STRIDE + kt + kk);
            #pragma unroll
            for (int k = 0; k < 4; k++)
                gv[k] = *(const float4*)(Gs + (kk + k) * D + c0);
            #pragma unroll
            for (int i = 0; i < 4; i++) {
                acc[i][0] += xa[i].x * gv[0].x + xa[i].y * gv[1].x + xa[i].z * gv[2].x + xa[i].w * gv[3].x;
                acc[i][1] += xa[i].x * gv[0].y + xa[i].y * gv[1].y + xa[i].z * gv[2].y + xa[i].w * gv[3].y;
                acc[i][2] += xa[i].x * gv[0].z + xa[i].y * gv[1].z + xa[i].z * gv[2].z + xa[i].w * gv[3].z;
                acc[i][3] += xa[i].x * gv[0].w + xa[i].y * gv[1].w + xa[i].z * gv[2].w + xa[i].w * gv[3].w;
            }
        }
    }

    float* op = out + ((size_t)b * T + (size_t)chunk * ROWS2) * D;
    #pragma unroll
    for (int i = 0; i < 4; i++)
        *(float4*)(op + (r0 + i) * D + c0) = make_float4(acc[i][0], acc[i][1], acc[i][2], acc[i][3]);
}

extern "C" void kernel_launch(void* const* d_in, const int* in_sizes, int n_in,
                              void* d_out, int out_size, void* d_ws, size_t ws_size,
                              hipStream_t stream) {
    const float* x = (const float*)d_in[0];
    float* out = (float*)d_out;

    const size_t part_elems = (size_t)BATCH * CHUNKS * D * D;   // 8.39M floats (32 MB)
    const size_t g_elems = (size_t)BATCH * D * D;               // 65536 floats
    const size_t need_bytes = (part_elems + g_elems) * sizeof(float);

    if (ws_size >= need_bytes) {
        float* part = (float*)d_ws;
        float* g = part + part_elems;
        k_partial_g<<<BATCH * CHUNKS, 256, 0, stream>>>(x, part);
        k_reduce_g<<<(int)(g_elems / 256), 256, 0, stream>>>(part, g);
        k_xg<<<BATCH * 64, 512, 0, stream>>>(x, g, out);
    } else {
        // Fallback (tiny ws): single-chunk-per-batch path would need atomics;
        // ws is known to be large in this harness, but keep a safe path.
        float* part = (float*)d_ws;
        float* g = part + part_elems;  // may alias beyond ws; unused in practice
        k_partial_g<<<BATCH * CHUNKS, 256, 0, stream>>>(x, part);
        k_reduce_g<<<(int)(g_elems / 256), 256, 0, stream>>>(part, g);
        k_xg<<<BATCH * 64, 512, 0, stream>>>(x, g, out);
    }
}

// Round 3
// 87.507 us; speedup vs baseline: 1.0511x; 1.0511x over previous
//
#include <hip/hip_runtime.h>

#define BATCH 4
#define T 4096
#define D 128
#define CHUNKS 64              // stage-1 blocks per batch
#define ROWS1 64               // rows per stage-1 block (T / CHUNKS)
#define ROWS2 32               // rows per stage-2 block
#define XS_STRIDE 132          // padded LDS stride for stage 2 (528 B: keeps b128 aligned, breaks 128-stride banking)

// ---------------- Stage 1: partial Gram matrices -----------------
// grid = BATCH*CHUNKS = 256 blocks of 256 threads (1 block/CU).
// Each block: G_part[d1][d2] = sum over its 64 rows of X[t,d1]*X[t,d2].
// Thread tile 8x8 (rows ty*8, cols {tx*4, 64+tx*4}) — 64 FMA per t-step vs
// 4 ds_read_b128 (~48 cyc) -> FMA-issue-bound. NO unroll pragma: round 2
// showed `#pragma unroll 4` here causes scratch spills (VGPR 52 < 64 live
// accumulators, 31 ms dispatch, VALUBusy 1%).
__global__ __launch_bounds__(256) void k_partial_g(const float* __restrict__ x,
                                                   float* __restrict__ part) {
    __shared__ float Xs[ROWS1 * D];          // 32 KB
    const int blk = blockIdx.x;
    const int b = blk / CHUNKS, chunk = blk % CHUNKS;
    const float* xp = x + ((size_t)b * T + (size_t)chunk * ROWS1) * D;
    const int tid = threadIdx.x;

    const float4* xp4 = (const float4*)xp;
    float4* Xs4 = (float4*)Xs;
    #pragma unroll
    for (int i = 0; i < (ROWS1 * D / 4) / 256; i++)
        Xs4[tid + i * 256] = xp4[tid + i * 256];
    __syncthreads();

    const int ty = tid >> 4, tx = tid & 15;
    const int r0 = ty * 8;
    const int c0 = tx * 4;

    float acc[8][8];
    #pragma unroll
    for (int i = 0; i < 8; i++)
        #pragma unroll
        for (int j = 0; j < 8; j++) acc[i][j] = 0.f;

    for (int t = 0; t < ROWS1; t++) {
        const float* row = Xs + t * D;
        float a[8], bv[8];
        #pragma unroll
        for (int i = 0; i < 8; i++) a[i] = row[r0 + i];
        #pragma unroll
        for (int j = 0; j < 4; j++) { bv[j] = row[c0 + j]; bv[4 + j] = row[64 + c0 + j]; }
        #pragma unroll
        for (int i = 0; i < 8; i++)
            #pragma unroll
            for (int j = 0; j < 8; j++) acc[i][j] += a[i] * bv[j];
    }

    float* pp = part + (size_t)blk * (D * D);
    #pragma unroll
    for (int i = 0; i < 8; i++) {
        *(float4*)(pp + (r0 + i) * D + c0)      = make_float4(acc[i][0], acc[i][1], acc[i][2], acc[i][3]);
        *(float4*)(pp + (r0 + i) * D + 64 + c0) = make_float4(acc[i][4], acc[i][5], acc[i][6], acc[i][7]);
    }
}

// ---------------- Stage 1b: reduce partials -> G -----------------
// grid = BATCH*D*D/256 = 256 blocks. Each thread sums CHUNKS strided values
// with 8 independent accumulators (deep MLP; lanes are coalesced within a slice).
__global__ __launch_bounds__(256) void k_reduce_g(const float* __restrict__ part,
                                                  float* __restrict__ g) {
    const int o = blockIdx.x * 256 + threadIdx.x;   // 0 .. BATCH*D*D
    const int b = o >> 14;                          // / 16384
    const int e = o & 16383;
    const float* p = part + ((size_t)b * CHUNKS) * (D * D) + e;
    float s[8];
    #pragma unroll
    for (int i = 0; i < 8; i++) s[i] = 0.f;
    for (int c = 0; c < CHUNKS; c += 8) {
        #pragma unroll
        for (int i = 0; i < 8; i++)
            s[i] += p[(size_t)(c + i) * (D * D)];
    }
    g[o] = ((s[0] + s[1]) + (s[2] + s[3])) + ((s[4] + s[5]) + (s[6] + s[7]));
}

// ---------------- Stage 2: out = X * G ---------------------------
// grid = BATCH*128 = 512 blocks of 256 threads -> 2 blocks/CU, 2 waves/SIMD.
// 32-row x 128-col tile; thread micro-tile 4x4. k in groups of 4 so every
// LDS read is an aligned ds_read_b128: xa broadcast across 32 lanes, gv
// lane-consecutive (conflict-free). LDS/FMA per 4k-group: 96 vs 128 cyc.
__global__ __launch_bounds__(256) void k_xg(const float* __restrict__ x,
                                            const float* __restrict__ g,
                                            float* __restrict__ out) {
    __shared__ float Xs[ROWS2 * XS_STRIDE];  // 16.9 KB
    __shared__ float Gs[32 * D];             // 16 KB
    const int blk = blockIdx.x;
    const int b = blk >> 7, chunk = blk & 127;
    const float* xp = x + ((size_t)b * T + (size_t)chunk * ROWS2) * D;
    const int tid = threadIdx.x;

    #pragma unroll
    for (int ii = 0; ii < (ROWS2 * D / 4) / 256; ii++) {
        int i = tid + ii * 256;
        int t = i >> 5, c4 = i & 31;
        *(float4*)(Xs + t * XS_STRIDE + c4 * 4) = ((const float4*)xp)[i];
    }

    const int ty = tid >> 5;                 // 0..7   -> row group
    const int cx = tid & 31;                 // 0..31  -> col group
    const int r0 = ty * 4;
    const int c0 = cx * 4;

    float acc[4][4];
    #pragma unroll
    for (int i = 0; i < 4; i++)
        #pragma unroll
        for (int j = 0; j < 4; j++) acc[i][j] = 0.f;

    const float* gb = g + (size_t)b * (D * D);
    for (int kt = 0; kt < D; kt += 32) {
        __syncthreads();                     // also covers initial Xs fill
        #pragma unroll
        for (int ii = 0; ii < (32 * D / 4) / 256; ii++)
            ((float4*)Gs)[tid + ii * 256] = ((const float4*)(gb + kt * D))[tid + ii * 256];
        __syncthreads();
        #pragma unroll
        for (int kk = 0; kk < 32; kk += 4) {
            float4 xa[4], gv[4];
            #pragma unroll
            for (int i = 0; i < 4; i++)
                xa[i] = *(const float4*)(Xs + (r0 + i) * XS_STRIDE + kt + kk);
            #pragma unroll
            for (int k = 0; k < 4; k++)
                gv[k] = *(const float4*)(Gs + (kk + k) * D + c0);
            #pragma unroll
            for (int i = 0; i < 4; i++) {
                acc[i][0] += xa[i].x * gv[0].x + xa[i].y * gv[1].x + xa[i].z * gv[2].x + xa[i].w * gv[3].x;
                acc[i][1] += xa[i].x * gv[0].y + xa[i].y * gv[1].y + xa[i].z * gv[2].y + xa[i].w * gv[3].y;
                acc[i][2] += xa[i].x * gv[0].z + xa[i].y * gv[1].z + xa[i].z * gv[2].z + xa[i].w * gv[3].z;
                acc[i][3] += xa[i].x * gv[0].w + xa[i].y * gv[1].w + xa[i].z * gv[2].w + xa[i].w * gv[3].w;
            }
        }
    }

    float* op = out + ((size_t)b * T + (size_t)chunk * ROWS2) * D;
    #pragma unroll
    for (int i = 0; i < 4; i++)
        *(float4*)(op + (r0 + i) * D + c0) = make_float4(acc[i][0], acc[i][1], acc[i][2], acc[i][3]);
}

extern "C" void kernel_launch(void* const* d_in, const int* in_sizes, int n_in,
                              void* d_out, int out_size, void* d_ws, size_t ws_size,
                              hipStream_t stream) {
    const float* x = (const float*)d_in[0];
    float* out = (float*)d_out;

    const size_t part_elems = (size_t)BATCH * CHUNKS * D * D;   // 4.19M floats (16.8 MB)
    float* part = (float*)d_ws;
    float* g = part + part_elems;

    k_partial_g<<<BATCH * CHUNKS, 256, 0, stream>>>(x, part);
    k_reduce_g<<<BATCH * D * D / 256, 256, 0, stream>>>(part, g);
    k_xg<<<BATCH * 128, 256, 0, stream>>>(x, g, out);
}

// Round 4
// 78.641 us; speedup vs baseline: 1.1696x; 1.1127x over previous
//
#include <hip/hip_runtime.h>

#define BATCH 4
#define T 4096
#define D 128
#define CHUNKS 64              // stage-1 blocks per batch
#define ROWS1 64               // rows per stage-1 block (T / CHUNKS)
#define ROWS2 64               // rows per stage-2 block
#define S2 136                 // bf16 LDS row stride (272 B: 16B-aligned rows, breaks 256B banking)

typedef __attribute__((ext_vector_type(4))) float f32x4;
typedef __attribute__((ext_vector_type(8))) short bf16x8;

// float -> bf16 bits, round-to-nearest-even (inputs are normal floats; no NaN in data)
__device__ __forceinline__ unsigned short f2b(float f) {
    unsigned u = __builtin_bit_cast(unsigned, f);
    u += 0x7FFFu + ((u >> 16) & 1u);
    return (unsigned short)(u >> 16);
}

// ---------------- Stage 1: partial Gram matrices (fp32 VALU) -----------------
// 256 blocks x 256 threads. 8x8 thread tile; at the fp32 vector-pipe issue
// floor (~3.4 us). NOTE: no unroll pragma on the t-loop — round 2 showed it
// spills the 64 accumulators (31 ms dispatch, VALUBusy 1%).
__global__ __launch_bounds__(256) void k_partial_g(const float* __restrict__ x,
                                                   float* __restrict__ part) {
    __shared__ float Xs[ROWS1 * D];          // 32 KB
    const int blk = blockIdx.x;
    const int b = blk / CHUNKS, chunk = blk % CHUNKS;
    const float* xp = x + ((size_t)b * T + (size_t)chunk * ROWS1) * D;
    const int tid = threadIdx.x;

    const float4* xp4 = (const float4*)xp;
    float4* Xs4 = (float4*)Xs;
    #pragma unroll
    for (int i = 0; i < (ROWS1 * D / 4) / 256; i++)
        Xs4[tid + i * 256] = xp4[tid + i * 256];
    __syncthreads();

    const int ty = tid >> 4, tx = tid & 15;
    const int r0 = ty * 8;
    const int c0 = tx * 4;

    float acc[8][8];
    #pragma unroll
    for (int i = 0; i < 8; i++)
        #pragma unroll
        for (int j = 0; j < 8; j++) acc[i][j] = 0.f;

    for (int t = 0; t < ROWS1; t++) {
        const float* row = Xs + t * D;
        float a[8], bv[8];
        #pragma unroll
        for (int i = 0; i < 8; i++) a[i] = row[r0 + i];
        #pragma unroll
        for (int j = 0; j < 4; j++) { bv[j] = row[c0 + j]; bv[4 + j] = row[64 + c0 + j]; }
        #pragma unroll
        for (int i = 0; i < 8; i++)
            #pragma unroll
            for (int j = 0; j < 8; j++) acc[i][j] += a[i] * bv[j];
    }

    float* pp = part + (size_t)blk * (D * D);
    #pragma unroll
    for (int i = 0; i < 8; i++) {
        *(float4*)(pp + (r0 + i) * D + c0)      = make_float4(acc[i][0], acc[i][1], acc[i][2], acc[i][3]);
        *(float4*)(pp + (r0 + i) * D + 64 + c0) = make_float4(acc[i][4], acc[i][5], acc[i][6], acc[i][7]);
    }
}

// ---------------- Stage 1b: reduce partials -> G (bf16 out) -----------------
// 256 blocks x 256 threads; one G element per thread, 8-deep MLP.
// Emits bf16 G for the MFMA stage-2 (G symmetric -> row-major IS col-major).
__global__ __launch_bounds__(256) void k_reduce_g(const float* __restrict__ part,
                                                  unsigned short* __restrict__ g) {
    const int o = blockIdx.x * 256 + threadIdx.x;   // 0 .. BATCH*D*D
    const int b = o >> 14;
    const int e = o & 16383;
    const float* p = part + ((size_t)b * CHUNKS) * (D * D) + e;
    float s[8];
    #pragma unroll
    for (int i = 0; i < 8; i++) s[i] = 0.f;
    for (int c = 0; c < CHUNKS; c += 8) {
        #pragma unroll
        for (int i = 0; i < 8; i++)
            s[i] += p[(size_t)(c + i) * (D * D)];
    }
    float sum = ((s[0] + s[1]) + (s[2] + s[3])) + ((s[4] + s[5]) + (s[6] + s[7]));
    g[o] = f2b(sum);
}

// ---------------- Stage 2: out = X * G via bf16 MFMA -----------------
// 256 blocks x 256 threads; each block a 64-row x 128-col output tile.
// Wave w owns rows [w*16, w*16+16): 8 tiles of 16x16, K=128 in 4 steps of 32.
// A-frag: X row-major, lane reads Xs[w*16 + (lane&15)][k0 + (lane>>4)*8 .. +8]
//   (verified A-layout: A[m=lane&15][k=quad*8+j], m120).
// B-frag: B[k][n] with n=lane&15 -> G[k][n] = G[n][k] (symmetry) -> Gs row-major,
//   identical read pattern (the m92/m97 "B^T input" trick).
// C/D: col=lane&15, row=quad*4+reg (verified m89/m91).
__global__ __launch_bounds__(256) void k_xg_mfma(const float* __restrict__ x,
                                                 const unsigned short* __restrict__ g,
                                                 float* __restrict__ out) {
    __shared__ unsigned short Xs[ROWS2 * S2];   // 17.4 KB
    __shared__ unsigned short Gs[D * S2];       // 34.8 KB
    const int blk = blockIdx.x;
    const int b = blk >> 6, chunk = blk & 63;
    const float* xp = x + ((size_t)b * T + (size_t)chunk * ROWS2) * D;
    const unsigned short* gp = g + (size_t)b * (D * D);
    const int tid = threadIdx.x;

    // Stage X: fp32 global (coalesced float4) -> bf16 LDS (8 B ushort4 writes).
    {
        const int dg = tid & 31, tr = tid >> 5;     // 32 float4-cols x 8 rows/pass
        #pragma unroll
        for (int ii = 0; ii < 8; ii++) {
            const int t = tr + ii * 8;
            float4 v = ((const float4*)(xp + t * D))[dg];
            ushort4 pk;
            pk.x = f2b(v.x); pk.y = f2b(v.y); pk.z = f2b(v.z); pk.w = f2b(v.w);
            *(ushort4*)(Xs + t * S2 + dg * 4) = pk;   // byte addr t*272 + dg*8: 8B-aligned
        }
    }
    // Stage G: already bf16; 16 B copies.
    {
        const int f4 = tid & 15, r = tid >> 4;      // 16 x16B-chunks per row, 16 rows/pass
        #pragma unroll
        for (int ii = 0; ii < 8; ii++) {
            const int row = r + ii * 16;
            uint4 gv = ((const uint4*)(gp + row * D))[f4];
            *(uint4*)(Gs + row * S2 + f4 * 8) = gv;   // byte addr row*272 + f4*16: 16B-aligned
        }
    }
    __syncthreads();

    const int lane = tid & 63, w = tid >> 6;
    const int m = lane & 15, q = lane >> 4;

    f32x4 acc[8];
    #pragma unroll
    for (int ni = 0; ni < 8; ni++) acc[ni] = (f32x4){0.f, 0.f, 0.f, 0.f};

    const unsigned short* arow = Xs + (w * 16 + m) * S2 + q * 8;
    const unsigned short* brow = Gs + m * S2 + q * 8;

    #pragma unroll
    for (int s = 0; s < 4; s++) {
        bf16x8 a = *(const bf16x8*)(arow + s * 32);
        #pragma unroll
        for (int ni = 0; ni < 8; ni++) {
            bf16x8 bb = *(const bf16x8*)(brow + ni * 16 * S2 + s * 32);
            acc[ni] = __builtin_amdgcn_mfma_f32_16x16x32_bf16(a, bb, acc[ni], 0, 0, 0);
        }
    }

    float* op = out + ((size_t)b * T + (size_t)chunk * ROWS2) * D;
    const int row0 = w * 16 + q * 4;
    #pragma unroll
    for (int ni = 0; ni < 8; ni++)
        #pragma unroll
        for (int r = 0; r < 4; r++)
            op[(row0 + r) * D + ni * 16 + m] = acc[ni][r];
}

extern "C" void kernel_launch(void* const* d_in, const int* in_sizes, int n_in,
                              void* d_out, int out_size, void* d_ws, size_t ws_size,
                              hipStream_t stream) {
    const float* x = (const float*)d_in[0];
    float* out = (float*)d_out;

    const size_t part_elems = (size_t)BATCH * CHUNKS * D * D;   // 4.19M floats (16.8 MB)
    float* part = (float*)d_ws;
    unsigned short* g = (unsigned short*)(part + part_elems);   // bf16 G, 128 KB

    k_partial_g<<<BATCH * CHUNKS, 256, 0, stream>>>(x, part);
    k_reduce_g<<<BATCH * D * D / 256, 256, 0, stream>>>(part, g);
    k_xg_mfma<<<BATCH * 64, 256, 0, stream>>>(x, g, out);
}

// Round 5
// 68.867 us; speedup vs baseline: 1.3356x; 1.1419x over previous
//
#include <hip/hip_runtime.h>

#define BATCH 4
#define T 4096
#define D 128
#define CHUNKS 64              // gram chunks per batch (64 rows each)
#define ROWS1 64               // rows per gram block
#define ROWS2 64               // rows per stage-2 block
#define ST1 72                 // XT LDS stride in ushorts (144 B = 36 words ≡ 4 mod 32)
#define S2 136                 // stage-2 LDS stride in ushorts (272 B)

typedef __attribute__((ext_vector_type(4))) float f32x4;
typedef __attribute__((ext_vector_type(8))) short bf16x8;

// float -> bf16 bits, round-to-nearest-even
__device__ __forceinline__ unsigned short f2b(float f) {
    unsigned u = __builtin_bit_cast(unsigned, f);
    u += 0x7FFFu + ((u >> 16) & 1u);
    return (unsigned short)(u >> 16);
}
__device__ __forceinline__ float b2f(unsigned short h) {
    return __builtin_bit_cast(float, (unsigned)h << 16);
}

// ---------------- Stage 1: partial Gram via bf16 MFMA -----------------
// 256 blocks x 256 threads; block = (batch, 64-row chunk).
// LDS holds XT[d][t] (transposed, bf16): both A (=X^T row-major) and
// B (B^T = X^T row-major, m92 trick) fragments of G = X^T X read it
// contiguously in k=t. Transpose happens on the staging write: thread
// loads float2 from rows t,t+1 (64B-coalesced), packs 2 uints, writes
// word (36d + tp) -> banks (8*(lane&7) + tp) mod 32, <=2-way = free.
// Wave w computes m-tiles {2w,2w+1} x 8 n-tiles, K=64 in 2 MFMA steps.
__global__ __launch_bounds__(256) void k_gram(const float* __restrict__ x,
                                              unsigned short* __restrict__ part) {
    __shared__ unsigned short XT[D * ST1];   // 18.4 KB
    const int blk = blockIdx.x;
    const int b = blk >> 6, chunk = blk & 63;
    const float* xp = x + ((size_t)b * T + (size_t)chunk * ROWS1) * D;
    const int tid = threadIdx.x;

    #pragma unroll
    for (int pass = 0; pass < 8; pass++) {
        const int slot = (tid >> 6) + 4 * pass;      // 0..31
        const int dd = 2 * (tid & 7) + 16 * (slot & 7);    // even d base, 0..126
        const int tpg = ((tid >> 3) & 7) + 8 * (slot >> 3); // t-pair 0..31
        const int t = 2 * tpg;
        float2 f0 = *(const float2*)(xp + (size_t)t * D + dd);
        float2 f1 = *(const float2*)(xp + (size_t)(t + 1) * D + dd);
        unsigned u0 = (unsigned)f2b(f0.x) | ((unsigned)f2b(f1.x) << 16);
        unsigned u1 = (unsigned)f2b(f0.y) | ((unsigned)f2b(f1.y) << 16);
        *(unsigned*)(XT + dd * ST1 + 2 * tpg) = u0;        // XT[dd][t..t+1]
        *(unsigned*)(XT + (dd + 1) * ST1 + 2 * tpg) = u1;  // XT[dd+1][t..t+1]
    }
    __syncthreads();

    const int lane = tid & 63, w = tid >> 6;
    const int m = lane & 15, q = lane >> 4;
    const int m0 = w * 32;

    f32x4 acc[2][8];
    #pragma unroll
    for (int mi = 0; mi < 2; mi++)
        #pragma unroll
        for (int ni = 0; ni < 8; ni++) acc[mi][ni] = (f32x4){0.f, 0.f, 0.f, 0.f};

    #pragma unroll
    for (int s = 0; s < 2; s++) {            // k0 = s*32
        bf16x8 av[2], bv[8];
        #pragma unroll
        for (int mi = 0; mi < 2; mi++)
            av[mi] = *(const bf16x8*)(XT + (m0 + mi * 16 + m) * ST1 + q * 8 + s * 32);
        #pragma unroll
        for (int ni = 0; ni < 8; ni++)
            bv[ni] = *(const bf16x8*)(XT + (ni * 16 + m) * ST1 + q * 8 + s * 32);
        #pragma unroll
        for (int mi = 0; mi < 2; mi++)
            #pragma unroll
            for (int ni = 0; ni < 8; ni++)
                acc[mi][ni] = __builtin_amdgcn_mfma_f32_16x16x32_bf16(av[mi], bv[ni], acc[mi][ni], 0, 0, 0);
    }

    // Store partial G (bf16). C/D layout: col=lane&15, row=q*4+reg (m89/m91).
    unsigned short* pp = part + (size_t)blk * (D * D);
    #pragma unroll
    for (int mi = 0; mi < 2; mi++)
        #pragma unroll
        for (int ni = 0; ni < 8; ni++) {
            const int row0 = m0 + mi * 16 + q * 4;
            const int col = ni * 16 + m;
            #pragma unroll
            for (int r = 0; r < 4; r++)
                pp[(size_t)(row0 + r) * D + col] = f2b(acc[mi][ni][r]);
        }
}

// ---------------- Stage 1b: reduce bf16 partials -> bf16 G -----------------
// 256 blocks x 256 threads; one G element/thread, 8 independent accumulators.
__global__ __launch_bounds__(256) void k_reduce_g(const unsigned short* __restrict__ part,
                                                  unsigned short* __restrict__ g) {
    const int o = blockIdx.x * 256 + threadIdx.x;   // 0 .. BATCH*D*D
    const int b = o >> 14;
    const int e = o & 16383;
    const unsigned short* p = part + ((size_t)b * CHUNKS) * (D * D) + e;
    float s[8];
    #pragma unroll
    for (int i = 0; i < 8; i++) s[i] = 0.f;
    for (int c = 0; c < CHUNKS; c += 8) {
        #pragma unroll
        for (int i = 0; i < 8; i++)
            s[i] += b2f(p[(size_t)(c + i) * (D * D)]);
    }
    float sum = ((s[0] + s[1]) + (s[2] + s[3])) + ((s[4] + s[5]) + (s[6] + s[7]));
    g[o] = f2b(sum);
}

// ---------------- Stage 2: out = X * G via bf16 MFMA -----------------
// (unchanged from round 4 — proven: 8.9 us win, absmax 128)
__global__ __launch_bounds__(256) void k_xg_mfma(const float* __restrict__ x,
                                                 const unsigned short* __restrict__ g,
                                                 float* __restrict__ out) {
    __shared__ unsigned short Xs[ROWS2 * S2];   // 17.4 KB
    __shared__ unsigned short Gs[D * S2];       // 34.8 KB
    const int blk = blockIdx.x;
    const int b = blk >> 6, chunk = blk & 63;
    const float* xp = x + ((size_t)b * T + (size_t)chunk * ROWS2) * D;
    const unsigned short* gp = g + (size_t)b * (D * D);
    const int tid = threadIdx.x;

    {
        const int dg = tid & 31, tr = tid >> 5;
        #pragma unroll
        for (int ii = 0; ii < 8; ii++) {
            const int t = tr + ii * 8;
            float4 v = ((const float4*)(xp + t * D))[dg];
            ushort4 pk;
            pk.x = f2b(v.x); pk.y = f2b(v.y); pk.z = f2b(v.z); pk.w = f2b(v.w);
            *(ushort4*)(Xs + t * S2 + dg * 4) = pk;
        }
    }
    {
        const int f4 = tid & 15, r = tid >> 4;
        #pragma unroll
        for (int ii = 0; ii < 8; ii++) {
            const int row = r + ii * 16;
            uint4 gv = ((const uint4*)(gp + row * D))[f4];
            *(uint4*)(Gs + row * S2 + f4 * 8) = gv;
        }
    }
    __syncthreads();

    const int lane = tid & 63, w = tid >> 6;
    const int m = lane & 15, q = lane >> 4;

    f32x4 acc[8];
    #pragma unroll
    for (int ni = 0; ni < 8; ni++) acc[ni] = (f32x4){0.f, 0.f, 0.f, 0.f};

    const unsigned short* arow = Xs + (w * 16 + m) * S2 + q * 8;
    const unsigned short* brow = Gs + m * S2 + q * 8;

    #pragma unroll
    for (int s = 0; s < 4; s++) {
        bf16x8 a = *(const bf16x8*)(arow + s * 32);
        #pragma unroll
        for (int ni = 0; ni < 8; ni++) {
            bf16x8 bb = *(const bf16x8*)(brow + ni * 16 * S2 + s * 32);
            acc[ni] = __builtin_amdgcn_mfma_f32_16x16x32_bf16(a, bb, acc[ni], 0, 0, 0);
        }
    }

    float* op = out + ((size_t)b * T + (size_t)chunk * ROWS2) * D;
    const int row0 = w * 16 + q * 4;
    #pragma unroll
    for (int ni = 0; ni < 8; ni++)
        #pragma unroll
        for (int r = 0; r < 4; r++)
            op[(row0 + r) * D + ni * 16 + m] = acc[ni][r];
}

extern "C" void kernel_launch(void* const* d_in, const int* in_sizes, int n_in,
                              void* d_out, int out_size, void* d_ws, size_t ws_size,
                              hipStream_t stream) {
    const float* x = (const float*)d_in[0];
    float* out = (float*)d_out;

    const size_t part_elems = (size_t)BATCH * CHUNKS * D * D;     // 4.19M bf16 (8.4 MB)
    unsigned short* part = (unsigned short*)d_ws;
    unsigned short* g = part + part_elems;                        // bf16 G, 128 KB

    k_gram<<<BATCH * CHUNKS, 256, 0, stream>>>(x, part);
    k_reduce_g<<<BATCH * D * D / 256, 256, 0, stream>>>(part, g);
    k_xg_mfma<<<BATCH * 64, 256, 0, stream>>>(x, g, out);
}